// Round 1
// 3157.385 us; speedup vs baseline: 1.1637x; 1.1637x over previous
//
#include <hip/hip_runtime.h>

// WordGenerator: bidirectional LSTM (H=256) + 3 stacked LSTM cells (H2=512) + vocab proj.
// Round 5: remove the per-step f32->bf16 hi/lo split entirely.
//  * Prep kernels split ALL MFMA operands (weights, embedded sequence, h0) into bf16
//    hi/lo planes once per launch; h outputs are written as hi/lo planes directly.
//  * k_step2 stages operand tiles via global_load_lds (width 16) into linear LDS
//    (bank-uniform for the frag-read pattern), 3-deep buffer, counted vmcnt(4),
//    one raw s_barrier per K-iter. 2x2 wave->frag map halves duplicate LDS reads.
//  * Gate exchange for the cell update via a small LDS transpose once per step.
//  * Numerically bit-identical to round 4 (same hi/lo decomposition, same 3-MFMA
//    order, same epilogue order).
//  * Old (round-4) path kept verbatim as fallback when ws_size < 31 MiB.

typedef __bf16 bf16x8 __attribute__((ext_vector_type(8)));
typedef __bf16 bf16x4v __attribute__((ext_vector_type(4)));
typedef float f32x4 __attribute__((ext_vector_type(4)));

__device__ __forceinline__ float sigm(float x) { return 1.0f / (1.0f + expf(-x)); }

// split 8 f32 into hi/lo bf16x8 (old path)
__device__ __forceinline__ void split8(const f32x4& a0, const f32x4& a1, bf16x8& h,
                                       bf16x8& l) {
#pragma unroll
  for (int j = 0; j < 4; ++j) {
    float f = a0[j];
    __bf16 hb = (__bf16)f;
    h[j] = hb;
    l[j] = (__bf16)(f - (float)hb);
  }
#pragma unroll
  for (int j = 0; j < 4; ++j) {
    float f = a1[j];
    __bf16 hb = (__bf16)f;
    h[4 + j] = hb;
    l[4 + j] = (__bf16)(f - (float)hb);
  }
}

__device__ __forceinline__ void glds16(const void* g, void* l) {
  __builtin_amdgcn_global_load_lds(
      (const __attribute__((address_space(1))) unsigned int*)g,
      (__attribute__((address_space(3))) unsigned int*)l, 16, 0, 0);
}

// -------------------- c-state init (f32 copy; inputs are pristine/read-only) ----------
__global__ __launch_bounds__(256) void k_init(const float* c0f, const float* c0b,
                                              const float* c01, const float* c02,
                                              const float* c03, float* cf, float* cb,
                                              float* c1, float* c2, float* c3) {
  const int i = blockIdx.x * 256 + threadIdx.x;  // 524288 total
  if (i < 65536) cf[i] = c0f[i];
  else if (i < 131072) cb[i - 65536] = c0b[i - 65536];
  else if (i < 262144) c1[i - 131072] = c01[i - 131072];
  else if (i < 393216) c2[i - 262144] = c02[i - 262144];
  else c3[i - 393216] = c03[i - 393216];
}

// ==================== OLD PATH (round 4, verbatim) ====================
template <int Kx, int Hc>
__device__ __forceinline__ void cell_core(const float* __restrict__ arow,
                                          const float* __restrict__ hrow,
                                          const float* __restrict__ wihrow,
                                          const float* __restrict__ whhrow,
                                          const float* __restrict__ bih,
                                          const float* __restrict__ bhh,
                                          float* __restrict__ cst,
                                          float* __restrict__ ho, int ldho, int m0,
                                          int j0, __bf16* lAh, __bf16* lAl,
                                          __bf16* lBh, __bf16* lBl) {
  const int tid = threadIdx.x, lane = tid & 63, wv = tid >> 6;
  const int mr = lane & 15, qk = (lane >> 4) * 8;
  const int srow = tid >> 2, scq = (tid & 3) * 8;  // staging: 64 rows x 32 cols
  constexpr int NX = Kx / 32, NT = NX + Hc / 32;

  auto gA = [&](int k, f32x4& x0, f32x4& x1) {
    const float* p = (k < NX) ? arow + k * 32 + scq : hrow + (k - NX) * 32 + scq;
    x0 = *(const f32x4*)p;
    x1 = *(const f32x4*)(p + 4);
  };
  auto gB = [&](int k, f32x4& x0, f32x4& x1) {
    const float* p = (k < NX) ? wihrow + k * 32 + scq : whhrow + (k - NX) * 32 + scq;
    x0 = *(const f32x4*)p;
    x1 = *(const f32x4*)(p + 4);
  };

  f32x4 acc[4] = {};
  f32x4 a0, a1, b0, b1;
  gA(0, a0, a1);
  gB(0, b0, b1);
  for (int k = 0; k < NT; ++k) {
    __syncthreads();
    bf16x8 hh, ll;
    split8(a0, a1, hh, ll);
    *(bf16x8*)(lAh + srow * 40 + scq) = hh;
    *(bf16x8*)(lAl + srow * 40 + scq) = ll;
    split8(b0, b1, hh, ll);
    *(bf16x8*)(lBh + srow * 40 + scq) = hh;
    *(bf16x8*)(lBl + srow * 40 + scq) = ll;
    if (k + 1 < NT) { gA(k + 1, a0, a1); gB(k + 1, b0, b1); }
    __syncthreads();
    bf16x8 ah = *(const bf16x8*)(lAh + (wv * 16 + mr) * 40 + qk);
    bf16x8 al = *(const bf16x8*)(lAl + (wv * 16 + mr) * 40 + qk);
#pragma unroll
    for (int G = 0; G < 4; ++G) {
      bf16x8 bh = *(const bf16x8*)(lBh + (G * 16 + mr) * 40 + qk);
      bf16x8 bl = *(const bf16x8*)(lBl + (G * 16 + mr) * 40 + qk);
      acc[G] = __builtin_amdgcn_mfma_f32_16x16x32_bf16(ah, bh, acc[G], 0, 0, 0);
      acc[G] = __builtin_amdgcn_mfma_f32_16x16x32_bf16(ah, bl, acc[G], 0, 0, 0);
      acc[G] = __builtin_amdgcn_mfma_f32_16x16x32_bf16(al, bh, acc[G], 0, 0, 0);
    }
  }

  const int jc = j0 + mr, r0 = (lane >> 4) * 4;
  float bs[4];
#pragma unroll
  for (int G = 0; G < 4; ++G) bs[G] = bih[G * Hc + jc] + bhh[G * Hc + jc];
#pragma unroll
  for (int r = 0; r < 4; ++r) {
    const int brow = m0 + wv * 16 + r0 + r;
    const size_t ci = (size_t)brow * Hc + jc;
    const float gi = acc[0][r] + bs[0];
    const float gf = acc[1][r] + bs[1];
    const float gg = acc[2][r] + bs[2];
    const float go = acc[3][r] + bs[3];
    const float cn = sigm(gf) * cst[ci] + sigm(gi) * tanhf(gg);
    const float hn = sigm(go) * tanhf(cn);
    cst[ci] = cn;
    ho[(size_t)brow * ldho + jc] = hn;
  }
}

struct P {
  const int* x;
  const float* emb;
  float *pairs, *h1a, *h2a, *h3a;
  float *cf, *cb, *c1, *c2, *c3;
  const float *Wihf, *Whhf, *bihf, *bhhf;
  const float *Wihb, *Whhb, *bihb, *bhhb;
  const float *W1ih, *W1hh, *b1ih, *b1hh;
  const float *W2ih, *W2hh, *b2ih, *b2hh;
  const float *W3ih, *W3hh, *b3ih, *b3hh;
  const float *h0f, *h0b, *h01, *h02, *h03;
};

__global__ __launch_bounds__(256) void k_step(P p, int s) {
  __shared__ __align__(16) __bf16 lAh[64 * 40];
  __shared__ __align__(16) __bf16 lAl[64 * 40];
  __shared__ __align__(16) __bf16 lBh[64 * 40];
  __shared__ __align__(16) __bf16 lBl[64 * 40];
  const int wg = blockIdx.x;
  const int srow = threadIdx.x >> 2;
  const int RING = 256 * 512;
  if (wg < 128) {
    const int dir = wg >> 6, widx = wg & 63, t = s;
    if (t >= 128) return;
    const int m0 = (widx >> 4) * 64, j0 = (widx & 15) * 16;
    const int wrow = (srow >> 4) * 256 + j0 + (srow & 15);
    const int tok = p.x[(dir == 0 ? t : 127 - t) * 256 + m0 + srow];
    const float* arow = p.emb + (size_t)tok * 256;
    const float* hrow =
        (t == 0) ? (dir == 0 ? p.h0f : p.h0b) + (size_t)(m0 + srow) * 256
                 : p.pairs + ((t - 1) & 3) * RING + (dir ? 256 : 0) +
                       (size_t)(m0 + srow) * 512;
    const float* Wih = dir ? p.Wihb : p.Wihf;
    const float* Whh = dir ? p.Whhb : p.Whhf;
    const float* bih = dir ? p.bihb : p.bihf;
    const float* bhh = dir ? p.bhhb : p.bhhf;
    float* ho = p.pairs + (t & 3) * RING + (dir ? 256 : 0);
    cell_core<256, 256>(arow, hrow, Wih + (size_t)wrow * 256, Whh + (size_t)wrow * 256,
                        bih, bhh, dir ? p.cb : p.cf, ho, 512, m0, j0, lAh, lAl, lBh,
                        lBl);
  } else {
    const int st = (wg - 128) >> 7;
    const int widx = (wg - 128) & 127;
    const int t = s - 1 - st;
    if (t < 0 || t >= 128) return;
    const int m0 = (widx >> 5) * 64, j0 = (widx & 31) * 16;
    const int wrow = (srow >> 4) * 512 + j0 + (srow & 15);
    const int ring = (t & 3) * RING, ringp = ((t - 1) & 3) * RING;
    const float *xin, *hp, *Wih, *Whh, *bih, *bhh;
    float *cst, *ho;
    if (st == 0) {
      xin = p.pairs + ring;
      hp = (t == 0) ? p.h01 : p.h1a + ringp;
      Wih = p.W1ih; Whh = p.W1hh; bih = p.b1ih; bhh = p.b1hh;
      cst = p.c1; ho = p.h1a + ring;
    } else if (st == 1) {
      xin = p.h1a + ring;
      hp = (t == 0) ? p.h02 : p.h2a + ringp;
      Wih = p.W2ih; Whh = p.W2hh; bih = p.b2ih; bhh = p.b2hh;
      cst = p.c2; ho = p.h2a + ring;
    } else {
      xin = p.h2a + ring;
      hp = (t == 0) ? p.h03 : p.h3a + ringp;
      Wih = p.W3ih; Whh = p.W3hh; bih = p.b3ih; bhh = p.b3hh;
      cst = p.c3; ho = p.h3a + ring;
    }
    cell_core<512, 512>(xin + (size_t)(m0 + srow) * 512, hp + (size_t)(m0 + srow) * 512,
                        Wih + (size_t)wrow * 512, Whh + (size_t)wrow * 512, bih, bhh,
                        cst, ho, 512, m0, j0, lAh, lAl, lBh, lBl);
  }
}

__global__ __launch_bounds__(256) void k_copy(const float* __restrict__ src,
                                              float* __restrict__ dst) {
  const int i = blockIdx.x * 256 + threadIdx.x;  // 131072
  dst[i] = src[i];
}

// -------------------- output projection: out = h3 @ Wout^T + bout (f32) -------------
__global__ __launch_bounds__(256) void k_out(const float* __restrict__ h3,
                                             const float* __restrict__ Wt,
                                             const float* __restrict__ bo,
                                             float* __restrict__ out) {
  __shared__ __align__(16) __bf16 sAh[64 * 40];
  __shared__ __align__(16) __bf16 sAl[64 * 40];
  __shared__ __align__(16) __bf16 sBh[64 * 40];
  __shared__ __align__(16) __bf16 sBl[64 * 40];
  const int tid = threadIdx.x, lane = tid & 63, wv = tid >> 6;
  const int mr = lane & 15, qk = (lane >> 4) * 8;
  const int mt = blockIdx.x & 3, n0 = (blockIdx.x >> 2) * 64;
  const int srow = tid >> 2, scq = (tid & 3) * 8;
  const int m0 = mt * 64;
  int wr = n0 + srow;
  if (wr > 50256) wr = 50256;
  f32x4 acc[4] = {};
  f32x4 a0 = *(const f32x4*)(h3 + (size_t)(m0 + srow) * 512 + scq);
  f32x4 a1 = *(const f32x4*)(h3 + (size_t)(m0 + srow) * 512 + scq + 4);
  f32x4 b0 = *(const f32x4*)(Wt + (size_t)wr * 512 + scq);
  f32x4 b1 = *(const f32x4*)(Wt + (size_t)wr * 512 + scq + 4);
  for (int k = 0; k < 16; ++k) {
    __syncthreads();
    bf16x8 hh, ll;
    split8(a0, a1, hh, ll);
    *(bf16x8*)(sAh + srow * 40 + scq) = hh;
    *(bf16x8*)(sAl + srow * 40 + scq) = ll;
    split8(b0, b1, hh, ll);
    *(bf16x8*)(sBh + srow * 40 + scq) = hh;
    *(bf16x8*)(sBl + srow * 40 + scq) = ll;
    if (k < 15) {
      const int kk = (k + 1) * 32;
      a0 = *(const f32x4*)(h3 + (size_t)(m0 + srow) * 512 + kk + scq);
      a1 = *(const f32x4*)(h3 + (size_t)(m0 + srow) * 512 + kk + scq + 4);
      b0 = *(const f32x4*)(Wt + (size_t)wr * 512 + kk + scq);
      b1 = *(const f32x4*)(Wt + (size_t)wr * 512 + kk + scq + 4);
    }
    __syncthreads();
    bf16x8 ah = *(const bf16x8*)(sAh + (wv * 16 + mr) * 40 + qk);
    bf16x8 al = *(const bf16x8*)(sAl + (wv * 16 + mr) * 40 + qk);
#pragma unroll
    for (int G = 0; G < 4; ++G) {
      bf16x8 bh = *(const bf16x8*)(sBh + (G * 16 + mr) * 40 + qk);
      bf16x8 bl = *(const bf16x8*)(sBl + (G * 16 + mr) * 40 + qk);
      acc[G] = __builtin_amdgcn_mfma_f32_16x16x32_bf16(ah, bh, acc[G], 0, 0, 0);
      acc[G] = __builtin_amdgcn_mfma_f32_16x16x32_bf16(ah, bl, acc[G], 0, 0, 0);
      acc[G] = __builtin_amdgcn_mfma_f32_16x16x32_bf16(al, bh, acc[G], 0, 0, 0);
    }
  }
  const int r0 = (lane >> 4) * 4;
#pragma unroll
  for (int G = 0; G < 4; ++G) {
    const int n = n0 + G * 16 + mr;
    if (n < 50257) {
      const float bv = bo[n];
#pragma unroll
      for (int r = 0; r < 4; ++r) {
        const int brow = m0 + wv * 16 + r0 + r;
        out[(size_t)brow * 50257 + n] = acc[G][r] + bv;
      }
    }
  }
}

// ==================== NEW PATH (round 5) ====================

// ---- prep: split f32 tensors into bf16 hi/lo planes ----
struct SJ { const float* s; __bf16* h; __bf16* l; };
struct SplitJobs { SJ j[15]; int pre[16]; };

__global__ __launch_bounds__(256) void k_split(SplitJobs sj) {
  const int e0 = blockIdx.x * 1024;
  int ji = 0;
  while (e0 >= sj.pre[ji + 1]) ++ji;
  const int off = e0 - sj.pre[ji] + threadIdx.x * 4;
  const SJ J = sj.j[ji];
  f32x4 v = *(const f32x4*)(J.s + off);
  bf16x4v h4, l4;
#pragma unroll
  for (int c = 0; c < 4; ++c) {
    __bf16 hb = (__bf16)v[c];
    h4[c] = hb;
    l4[c] = (__bf16)(v[c] - (float)hb);
  }
  *(bf16x4v*)(J.h + off) = h4;
  *(bf16x4v*)(J.l + off) = l4;
}

// gather embedded sequence (flat (T*B, 256)) and split into hi/lo planes
__global__ __launch_bounds__(256) void k_seqsplit(const int* __restrict__ x,
                                                  const float* __restrict__ emb,
                                                  __bf16* __restrict__ sh,
                                                  __bf16* __restrict__ sl) {
  const int i = (blockIdx.x * 256 + threadIdx.x) * 4;  // 8388608 elems total
  const int row = i >> 8;
  const int tok = x[row];
  f32x4 v = *(const f32x4*)(emb + (size_t)tok * 256 + (i & 255));
  bf16x4v h4, l4;
#pragma unroll
  for (int c = 0; c < 4; ++c) {
    __bf16 hb = (__bf16)v[c];
    h4[c] = hb;
    l4[c] = (__bf16)(v[c] - (float)hb);
  }
  *(bf16x4v*)(sh + i) = h4;
  *(bf16x4v*)(sl + i) = l4;
}

// ---- the pre-split LSTM cell tile ----
// Tile: 64 batch rows x 16 h-cols x 4 gates. 4 waves in a 2x2 (M-half x gate-pair)
// map: each wave 2x2 accs, 8 ds_read_b128 per K-iter, 12 MFMA. Staging: 4 planes
// (Ah/Al/Bh/Bl) of 64x32 bf16 via global_load_lds (1 wave-instr per plane per wave),
// 3-deep buffer, counted vmcnt(4), one raw s_barrier per K-iter.
template <int KX, int HC>
__device__ __forceinline__ void cell2(
    const __bf16* __restrict__ xh, const __bf16* __restrict__ xl, const int xst,
    const __bf16* __restrict__ hh, const __bf16* __restrict__ hl, const int hst,
    const __bf16* __restrict__ wxh, const __bf16* __restrict__ wxl,
    const __bf16* __restrict__ whh, const __bf16* __restrict__ whl,
    const float* __restrict__ bih, const float* __restrict__ bhh,
    float* __restrict__ cst, __bf16* __restrict__ ohh, __bf16* __restrict__ ohl,
    const int ost, float* __restrict__ of32, const int m0, const int j0,
    __bf16* sm) {
  const int tid = threadIdx.x, lane = tid & 63, wv = tid >> 6;
  const int mr = lane & 15, q8 = (lane >> 4) * 8;
  const int srow = lane >> 2, cbe = (lane & 3) * 8;  // staging row / elem-col
  constexpr int NX = KX / 32, NT = NX + HC / 32;
  const int mh = wv & 1, gh = wv >> 1;

  const size_t arow = (size_t)(m0 + wv * 16 + srow);
  const size_t brow = (size_t)(wv * HC + j0 + srow);  // wave = gate
  const __bf16* axh = xh + arow * xst + cbe;
  const __bf16* axl = xl + arow * xst + cbe;
  const __bf16* ahh = hh + arow * hst + cbe;
  const __bf16* ahl = hl + arow * hst + cbe;
  const __bf16* bxh = wxh + brow * KX + cbe;
  const __bf16* bxl = wxl + brow * KX + cbe;
  const __bf16* bhh2 = whh + brow * HC + cbe;
  const __bf16* bhl2 = whl + brow * HC + cbe;

  auto issue = [&](int kb, int bbuf) {
    const bool xp = kb < NX;
    const int ko = (xp ? kb : kb - NX) * 32;
    __bf16* d = sm + bbuf * 8192 + wv * 512;
    glds16((xp ? axh : ahh) + ko, d);
    glds16((xp ? axl : ahl) + ko, d + 2048);
    glds16((xp ? bxh : bhh2) + ko, d + 4096);
    glds16((xp ? bxl : bhl2) + ko, d + 6144);
  };

  f32x4 acc[2][2] = {};
  issue(0, 0);
  int bb = 0;
  for (int kb = 0; kb < NT; ++kb) {
    const int nb = (bb == 2) ? 0 : bb + 1;
    if (kb + 1 < NT) {
      issue(kb + 1, nb);
      asm volatile("s_waitcnt vmcnt(4)" ::: "memory");
    } else {
      asm volatile("s_waitcnt vmcnt(0)" ::: "memory");
    }
    __builtin_amdgcn_s_barrier();
    asm volatile("" ::: "memory");  // keep ds_reads below the barrier
    const __bf16* base = sm + bb * 8192;
    bf16x8 fah[2], fal[2], fbh[2], fbl[2];
#pragma unroll
    for (int i = 0; i < 2; ++i) {
      const int ra = ((2 * mh + i) * 16 + mr) * 32 + q8;
      const int rb = ((2 * gh + i) * 16 + mr) * 32 + q8;
      fah[i] = *(const bf16x8*)(base + ra);
      fal[i] = *(const bf16x8*)(base + 2048 + ra);
      fbh[i] = *(const bf16x8*)(base + 4096 + rb);
      fbl[i] = *(const bf16x8*)(base + 6144 + rb);
    }
#pragma unroll
    for (int am = 0; am < 2; ++am)
#pragma unroll
      for (int ag = 0; ag < 2; ++ag) {
        acc[am][ag] =
            __builtin_amdgcn_mfma_f32_16x16x32_bf16(fah[am], fbh[ag], acc[am][ag], 0, 0, 0);
        acc[am][ag] =
            __builtin_amdgcn_mfma_f32_16x16x32_bf16(fah[am], fbl[ag], acc[am][ag], 0, 0, 0);
        acc[am][ag] =
            __builtin_amdgcn_mfma_f32_16x16x32_bf16(fal[am], fbh[ag], acc[am][ag], 0, 0, 0);
      }
    bb = nb;
  }

  // ---- gate exchange + cell update (once per step) ----
  __syncthreads();                // all waves done reading sm before overlay write
  float* gb = (float*)sm;         // [4 gates][64 rows][20] f32 = 20480 B
  {
    const int r0 = (lane >> 4) * 4;
#pragma unroll
    for (int am = 0; am < 2; ++am)
#pragma unroll
      for (int ag = 0; ag < 2; ++ag) {
        const int g = 2 * gh + ag;
        const int rowb = (2 * mh + am) * 16 + r0;
#pragma unroll
        for (int r = 0; r < 4; ++r)
          gb[(g * 64 + rowb + r) * 20 + mr] = acc[am][ag][r];
      }
  }
  __syncthreads();
  const int row = tid >> 2, c0 = (tid & 3) * 4, jc = j0 + c0;
  f32x4 gi = *(const f32x4*)(gb + (0 * 64 + row) * 20 + c0);
  f32x4 gf = *(const f32x4*)(gb + (1 * 64 + row) * 20 + c0);
  f32x4 gg = *(const f32x4*)(gb + (2 * 64 + row) * 20 + c0);
  f32x4 go = *(const f32x4*)(gb + (3 * 64 + row) * 20 + c0);
  f32x4 bI = *(const f32x4*)(bih + jc) + *(const f32x4*)(bhh + jc);
  f32x4 bF = *(const f32x4*)(bih + HC + jc) + *(const f32x4*)(bhh + HC + jc);
  f32x4 bG = *(const f32x4*)(bih + 2 * HC + jc) + *(const f32x4*)(bhh + 2 * HC + jc);
  f32x4 bO = *(const f32x4*)(bih + 3 * HC + jc) + *(const f32x4*)(bhh + 3 * HC + jc);
  const size_t ci = (size_t)(m0 + row) * HC + jc;
  f32x4 cc = *(f32x4*)(cst + ci);
  f32x4 hn;
  bf16x4v h4, l4;
#pragma unroll
  for (int c = 0; c < 4; ++c) {
    const float I = sigm(gi[c] + bI[c]);
    const float F = sigm(gf[c] + bF[c]);
    const float G = tanhf(gg[c] + bG[c]);
    const float O = sigm(go[c] + bO[c]);
    const float cn = F * cc[c] + I * G;
    cc[c] = cn;
    const float hv = O * tanhf(cn);
    hn[c] = hv;
    const __bf16 hb = (__bf16)hv;
    h4[c] = hb;
    l4[c] = (__bf16)(hv - (float)hb);
  }
  *(f32x4*)(cst + ci) = cc;
  *(bf16x4v*)(ohh + (size_t)(m0 + row) * ost + jc) = h4;
  *(bf16x4v*)(ohl + (size_t)(m0 + row) * ost + jc) = l4;
  if (of32) *(f32x4*)(of32 + (size_t)(m0 + row) * HC + jc) = hn;
}

struct P2 {
  const __bf16 *seqh, *seql;
  const __bf16 *Wfh, *Wfl, *Ufh, *Ufl;
  const __bf16 *Wbh, *Wbl, *Ubh, *Ubl;
  const __bf16 *W1h, *W1l, *U1h, *U1l;
  const __bf16 *W2h, *W2l, *U2h, *U2l;
  const __bf16 *W3h, *W3l, *U3h, *U3l;
  const float *bihf, *bhhf, *bihb, *bhhb;
  const float *b1ih, *b1hh, *b2ih, *b2hh, *b3ih, *b3hh;
  const __bf16 *h0fh, *h0fl, *h0bh, *h0bl;
  const __bf16 *h01h, *h01l, *h02h, *h02l, *h03h, *h03l;
  __bf16 *prh, *prl, *h1h, *h1l, *h2h, *h2l, *h3h, *h3l;
  float *cf, *cb, *c1, *c2, *c3;
  float* h3f;
};

__global__ __launch_bounds__(256) void k_step2(P2 p, int s) {
  __shared__ __align__(16) __bf16 sm[3 * 4 * 2048];  // 48 KiB: 3 bufs x 4 planes
  const int wg = blockIdx.x;
  const int RING = 256 * 512;
  if (wg < 128) {
    const int dir = wg >> 6, widx = wg & 63, t = s;
    if (t >= 128) return;
    const int m0 = (widx >> 4) * 64, j0 = (widx & 15) * 16;
    const int tt = dir ? 127 - t : t;
    const __bf16* xh = p.seqh + (size_t)tt * 65536;
    const __bf16* xl = p.seql + (size_t)tt * 65536;
    const __bf16 *hh, *hl;
    int hst;
    if (t == 0) {
      hh = dir ? p.h0bh : p.h0fh;
      hl = dir ? p.h0bl : p.h0fl;
      hst = 256;
    } else {
      const size_t off = (size_t)((t - 1) & 3) * RING + (dir ? 256 : 0);
      hh = p.prh + off;
      hl = p.prl + off;
      hst = 512;
    }
    const size_t oo = (size_t)(t & 3) * RING + (dir ? 256 : 0);
    cell2<256, 256>(xh, xl, 256, hh, hl, hst, dir ? p.Wbh : p.Wfh,
                    dir ? p.Wbl : p.Wfl, dir ? p.Ubh : p.Ufh, dir ? p.Ubl : p.Ufl,
                    dir ? p.bihb : p.bihf, dir ? p.bhhb : p.bhhf,
                    dir ? p.cb : p.cf, p.prh + oo, p.prl + oo, 512, nullptr, m0, j0,
                    sm);
  } else {
    const int st = (wg - 128) >> 7;
    const int widx = (wg - 128) & 127;
    const int t = s - 1 - st;
    if (t < 0 || t >= 128) return;
    const int m0 = (widx >> 5) * 64, j0 = (widx & 31) * 16;
    const size_t ring = (size_t)(t & 3) * RING, ringp = (size_t)((t - 1) & 3) * RING;
    const __bf16 *xh, *xl, *hh, *hl, *wxh, *wxl, *whh, *whl;
    const float *bi, *bh2;
    float* cst;
    float* of = nullptr;
    __bf16 *oh, *ol;
    if (st == 0) {
      xh = p.prh + ring; xl = p.prl + ring;
      if (t == 0) { hh = p.h01h; hl = p.h01l; } else { hh = p.h1h + ringp; hl = p.h1l + ringp; }
      wxh = p.W1h; wxl = p.W1l; whh = p.U1h; whl = p.U1l;
      bi = p.b1ih; bh2 = p.b1hh; cst = p.c1; oh = p.h1h + ring; ol = p.h1l + ring;
    } else if (st == 1) {
      xh = p.h1h + ring; xl = p.h1l + ring;
      if (t == 0) { hh = p.h02h; hl = p.h02l; } else { hh = p.h2h + ringp; hl = p.h2l + ringp; }
      wxh = p.W2h; wxl = p.W2l; whh = p.U2h; whl = p.U2l;
      bi = p.b2ih; bh2 = p.b2hh; cst = p.c2; oh = p.h2h + ring; ol = p.h2l + ring;
    } else {
      xh = p.h2h + ring; xl = p.h2l + ring;
      if (t == 0) { hh = p.h03h; hl = p.h03l; } else { hh = p.h3h + ringp; hl = p.h3l + ringp; }
      wxh = p.W3h; wxl = p.W3l; whh = p.U3h; whl = p.U3l;
      bi = p.b3ih; bh2 = p.b3hh; cst = p.c3; oh = p.h3h + ring; ol = p.h3l + ring;
      if (t == 127) of = p.h3f;
    }
    cell2<512, 512>(xh, xl, 512, hh, hl, 512, wxh, wxl, whh, whl, bi, bh2, cst, oh,
                    ol, 512, of, m0, j0, sm);
  }
}

// -------------------- host --------------------
extern "C" void kernel_launch(void* const* d_in, const int* in_sizes, int n_in,
                              void* d_out, int out_size, void* d_ws, size_t ws_size,
                              hipStream_t stream) {
  (void)in_sizes; (void)n_in; (void)out_size;

  const size_t MB = 1ull << 20;
  const bool packA = ws_size >= 44 * MB;
  const bool packB = !packA && ws_size >= 31 * MB;

  if (packA || packB) {
    // ---------- round-5 path ----------
    char* pw = (char*)d_ws;
    char* po = (char*)d_out;  // d_out scratch is dead before k_out writes it
    auto tw = [&](size_t n) { char* r = pw; pw += (n + 255) & ~(size_t)255; return r; };
    auto to = [&](size_t n) { char* r = po; po += (n + 255) & ~(size_t)255; return r; };

    float* h3f = (float*)tw(512 * 1024);  // k_out input: must stay out of d_out
    __bf16* seqh = (__bf16*)to(16 * MB);
    __bf16* seql = (__bf16*)to(16 * MB);

    const size_t WSM = 524288, WBG = 2097152;  // plane bytes: 1024x256 / 2048x512
    __bf16 *Wfh = (__bf16*)tw(WSM), *Wfl = (__bf16*)tw(WSM);
    __bf16 *Ufh = (__bf16*)tw(WSM), *Ufl = (__bf16*)tw(WSM);
    __bf16 *Wbh = (__bf16*)tw(WSM), *Wbl = (__bf16*)tw(WSM);
    __bf16 *Ubh = (__bf16*)tw(WSM), *Ubl = (__bf16*)tw(WSM);
    __bf16 *W1h = (__bf16*)tw(WBG), *W1l = (__bf16*)tw(WBG);
    __bf16 *U1h = (__bf16*)tw(WBG), *U1l = (__bf16*)tw(WBG);
    __bf16 *W2h = (__bf16*)tw(WBG), *W2l = (__bf16*)tw(WBG);
    __bf16 *U2h = (__bf16*)tw(WBG), *U2l = (__bf16*)tw(WBG);
    __bf16 *W3h = (__bf16*)tw(WBG), *W3l = (__bf16*)tw(WBG);
    __bf16 *U3h = (__bf16*)tw(WBG), *U3l = (__bf16*)tw(WBG);

    auto tr = [&](size_t n) { return packA ? tw(n) : to(n); };
    __bf16* h0fh = (__bf16*)tr(131072);
    __bf16* h0fl = (__bf16*)tr(131072);
    __bf16* h0bh = (__bf16*)tr(131072);
    __bf16* h0bl = (__bf16*)tr(131072);
    __bf16* h01h = (__bf16*)tr(262144);
    __bf16* h01l = (__bf16*)tr(262144);
    __bf16* h02h = (__bf16*)tr(262144);
    __bf16* h02l = (__bf16*)tr(262144);
    __bf16* h03h = (__bf16*)tr(262144);
    __bf16* h03l = (__bf16*)tr(262144);
    const size_t RB = 4ull * 131072 * 2;  // ring planes: 4 slots x 256x512 bf16
    __bf16* prh = (__bf16*)tr(RB);
    __bf16* prl = (__bf16*)tr(RB);
    __bf16* h1h = (__bf16*)tr(RB);
    __bf16* h1l = (__bf16*)tr(RB);
    __bf16* h2h = (__bf16*)tr(RB);
    __bf16* h2l = (__bf16*)tr(RB);
    __bf16* h3h = (__bf16*)tr(RB);
    __bf16* h3l = (__bf16*)tr(RB);
    float* cf = (float*)tr(262144);
    float* cb = (float*)tr(262144);
    float* c1 = (float*)tr(524288);
    float* c2 = (float*)tr(524288);
    float* c3 = (float*)tr(524288);

    // split jobs: 10 weight tensors + 5 h0 tensors (all sizes multiple of 1024)
    SplitJobs sj;
    int np = 0, pre = 0;
    auto addj = [&](const void* s, __bf16* h, __bf16* l, int n) {
      sj.j[np].s = (const float*)s; sj.j[np].h = h; sj.j[np].l = l;
      sj.pre[np] = pre; pre += n; ++np;
    };
    addj(d_in[2], Wfh, Wfl, 262144);   // Wih_f
    addj(d_in[3], Ufh, Ufl, 262144);   // Whh_f
    addj(d_in[6], Wbh, Wbl, 262144);   // Wih_b
    addj(d_in[7], Ubh, Ubl, 262144);   // Whh_b
    addj(d_in[10], W1h, W1l, 1048576);
    addj(d_in[11], U1h, U1l, 1048576);
    addj(d_in[14], W2h, W2l, 1048576);
    addj(d_in[15], U2h, U2l, 1048576);
    addj(d_in[18], W3h, W3l, 1048576);
    addj(d_in[19], U3h, U3l, 1048576);
    addj(d_in[24], h0fh, h0fl, 65536);
    addj(d_in[26], h0bh, h0bl, 65536);
    addj(d_in[28], h01h, h01l, 131072);
    addj(d_in[30], h02h, h02l, 131072);
    addj(d_in[32], h03h, h03l, 131072);
    sj.pre[np] = pre;  // 7864320

    P2 p;
    p.seqh = seqh; p.seql = seql;
    p.Wfh = Wfh; p.Wfl = Wfl; p.Ufh = Ufh; p.Ufl = Ufl;
    p.Wbh = Wbh; p.Wbl = Wbl; p.Ubh = Ubh; p.Ubl = Ubl;
    p.W1h = W1h; p.W1l = W1l; p.U1h = U1h; p.U1l = U1l;
    p.W2h = W2h; p.W2l = W2l; p.U2h = U2h; p.U2l = U2l;
    p.W3h = W3h; p.W3l = W3l; p.U3h = U3h; p.U3l = U3l;
    p.bihf = (const float*)d_in[4]; p.bhhf = (const float*)d_in[5];
    p.bihb = (const float*)d_in[8]; p.bhhb = (const float*)d_in[9];
    p.b1ih = (const float*)d_in[12]; p.b1hh = (const float*)d_in[13];
    p.b2ih = (const float*)d_in[16]; p.b2hh = (const float*)d_in[17];
    p.b3ih = (const float*)d_in[20]; p.b3hh = (const float*)d_in[21];
    p.h0fh = h0fh; p.h0fl = h0fl; p.h0bh = h0bh; p.h0bl = h0bl;
    p.h01h = h01h; p.h01l = h01l; p.h02h = h02h; p.h02l = h02l;
    p.h03h = h03h; p.h03l = h03l;
    p.prh = prh; p.prl = prl; p.h1h = h1h; p.h1l = h1l;
    p.h2h = h2h; p.h2l = h2l; p.h3h = h3h; p.h3l = h3l;
    p.cf = cf; p.cb = cb; p.c1 = c1; p.c2 = c2; p.c3 = c3;
    p.h3f = h3f;

    k_split<<<dim3(7680), dim3(256), 0, stream>>>(sj);
    k_seqsplit<<<dim3(8192), dim3(256), 0, stream>>>((const int*)d_in[0],
                                                     (const float*)d_in[1], seqh, seql);
    k_init<<<dim3(2048), dim3(256), 0, stream>>>(
        (const float*)d_in[25], (const float*)d_in[27], (const float*)d_in[29],
        (const float*)d_in[31], (const float*)d_in[33], cf, cb, c1, c2, c3);

    for (int s = 0; s < 131; ++s)
      k_step2<<<dim3(512), dim3(256), 0, stream>>>(p, s);

    k_out<<<dim3(3144), dim3(256), 0, stream>>>(h3f, (const float*)d_in[22],
                                                (const float*)d_in[23], (float*)d_out);
    return;
  }

  // ---------- round-4 fallback path (verbatim) ----------
  char* wsp = (char*)d_ws;
  float* h3c = (float*)wsp;

  const size_t SMALL = 1ull << 19, BIG = 11ull << 20;
  char* w = (ws_size >= SMALL + BIG + (1ull << 20)) ? wsp + SMALL : (char*)d_out;
  auto take = [&](size_t bytes) {
    char* r = w;
    w += (bytes + 255) & ~(size_t)255;
    return r;
  };
  float* pairs = (float*)take(4ull * 256 * 512 * 4);
  float* h1a = (float*)take(4ull * 256 * 512 * 4);
  float* h2a = (float*)take(4ull * 256 * 512 * 4);
  float* h3a = (float*)take(4ull * 256 * 512 * 4);
  float* cf = (float*)take(256ull * 256 * 4);
  float* cb = (float*)take(256ull * 256 * 4);
  float* c1 = (float*)take(256ull * 512 * 4);
  float* c2 = (float*)take(256ull * 512 * 4);
  float* c3 = (float*)take(256ull * 512 * 4);

  P p;
  p.x = (const int*)d_in[0];
  p.emb = (const float*)d_in[1];
  p.pairs = pairs; p.h1a = h1a; p.h2a = h2a; p.h3a = h3a;
  p.cf = cf; p.cb = cb; p.c1 = c1; p.c2 = c2; p.c3 = c3;
  p.Wihf = (const float*)d_in[2];  p.Whhf = (const float*)d_in[3];
  p.bihf = (const float*)d_in[4];  p.bhhf = (const float*)d_in[5];
  p.Wihb = (const float*)d_in[6];  p.Whhb = (const float*)d_in[7];
  p.bihb = (const float*)d_in[8];  p.bhhb = (const float*)d_in[9];
  p.W1ih = (const float*)d_in[10]; p.W1hh = (const float*)d_in[11];
  p.b1ih = (const float*)d_in[12]; p.b1hh = (const float*)d_in[13];
  p.W2ih = (const float*)d_in[14]; p.W2hh = (const float*)d_in[15];
  p.b2ih = (const float*)d_in[16]; p.b2hh = (const float*)d_in[17];
  p.W3ih = (const float*)d_in[18]; p.W3hh = (const float*)d_in[19];
  p.b3ih = (const float*)d_in[20]; p.b3hh = (const float*)d_in[21];
  const float* Wout = (const float*)d_in[22];
  const float* bout = (const float*)d_in[23];
  p.h0f = (const float*)d_in[24]; p.h0b = (const float*)d_in[26];
  p.h01 = (const float*)d_in[28]; p.h02 = (const float*)d_in[30];
  p.h03 = (const float*)d_in[32];

  k_init<<<dim3(2048), dim3(256), 0, stream>>>(
      (const float*)d_in[25], (const float*)d_in[27], (const float*)d_in[29],
      (const float*)d_in[31], (const float*)d_in[33], cf, cb, c1, c2, c3);

  for (int s = 0; s < 131; ++s)
    k_step<<<dim3(512), dim3(256), 0, stream>>>(p, s);

  k_copy<<<dim3(512), dim3(256), 0, stream>>>(h3a + 3 * (256 * 512), h3c);
  k_out<<<dim3(3144), dim3(256), 0, stream>>>(h3c, Wout, bout, (float*)d_out);
}